// Round 1
// baseline (536.360 us; speedup 1.0000x reference)
//
#include <hip/hip_runtime.h>
#include <stdint.h>

// ---------------------------------------------------------------------------
// UpBlock: 5 chained sparse convs (gather-GEMM), bf16 MFMA, no LDS.
// out[i] = sum_k feats[nbr[k,i]] @ W[k]; BN+LeakyReLU epilogues; skip add on L2.
// A-fragments are gathered directly from global (rows are 128/256B contiguous,
// L2/L3 resident); B-fragments read from weights pre-packed into MFMA fragment
// order (fully coalesced).
// mfma_f32_32x32x16_bf16:
//   A[m=lane&31][k=(lane>>5)*8+j], B[k=(lane>>5)*8+j][n=lane&31]
//   C/D: col=lane&31, row=(reg&3)+8*(reg>>2)+4*(lane>>5)
// ---------------------------------------------------------------------------

typedef __bf16 bf16x8 __attribute__((ext_vector_type(8)));
typedef float f32x16 __attribute__((ext_vector_type(16)));

__device__ __forceinline__ uint16_t f2bf(float f) {
    uint32_t u = __builtin_bit_cast(uint32_t, f);
    u = (u + 0x7fffu + ((u >> 16) & 1u)) >> 16;   // round-to-nearest-even
    return (uint16_t)u;
}

__device__ __forceinline__ bf16x8 ldb8(const uint16_t* p) {
    return __builtin_bit_cast(bf16x8, *reinterpret_cast<const uint4*>(p));
}

// --- convert x_feats (f32) -> bf16, 8 elems/thread --------------------------
__global__ void convert_x(const float* __restrict__ in, uint16_t* __restrict__ out, int n8) {
    int t = blockIdx.x * blockDim.x + threadIdx.x;
    if (t >= n8) return;
    const float4* p = reinterpret_cast<const float4*>(in) + 2 * (size_t)t;
    float4 f0 = p[0], f1 = p[1];
    uint32_t w0 = (uint32_t)f2bf(f0.x) | ((uint32_t)f2bf(f0.y) << 16);
    uint32_t w1 = (uint32_t)f2bf(f0.z) | ((uint32_t)f2bf(f0.w) << 16);
    uint32_t w2 = (uint32_t)f2bf(f1.x) | ((uint32_t)f2bf(f1.y) << 16);
    uint32_t w3 = (uint32_t)f2bf(f1.z) | ((uint32_t)f2bf(f1.w) << 16);
    uint4 v; v.x = w0; v.y = w1; v.z = w2; v.w = w3;
    *reinterpret_cast<uint4*>(out + 8 * (size_t)t) = v;
}

// --- pack weights into MFMA B-fragment order + BN scale/shift ---------------
// dst element [(((k*S + s)*2 + nt)*64 + lane)*8 + j] = bf16(W[k][ci][c])
//   ci = s*16 + (lane>>5)*8 + j,  c = nt*32 + (lane&31),  S = CIN/16
__global__ void pack_weights(const float* __restrict__ w1, const float* __restrict__ wt,
                             const float* __restrict__ w2, const float* __restrict__ w3,
                             const float* __restrict__ w4, const float* __restrict__ bn,
                             uint16_t* __restrict__ p1, uint16_t* __restrict__ pt,
                             uint16_t* __restrict__ p2, uint16_t* __restrict__ p3,
                             uint16_t* __restrict__ p4, float* __restrict__ bnps) {
    int w = blockIdx.y;
    int t = blockIdx.x * blockDim.x + threadIdx.x;
    if (w == 5) {  // BN scale/shift precompute: bnps[l][0][c]=scale, [l][1][c]=shift
        if (t < 256) {
            int l = t >> 6, c = t & 63;
            float g = bn[(l * 4 + 0) * 64 + c];
            float b = bn[(l * 4 + 1) * 64 + c];
            float m = bn[(l * 4 + 2) * 64 + c];
            float v = bn[(l * 4 + 3) * 64 + c];
            float sc = g * rsqrtf(v + 1e-5f);
            bnps[(l * 2 + 0) * 64 + c] = sc;
            bnps[(l * 2 + 1) * 64 + c] = b - m * sc;
        }
        return;
    }
    const float* src; uint16_t* dst; int K, CIN;
    switch (w) {
        case 0:  src = w1; dst = p1; K = 27; CIN = 128; break;
        case 1:  src = wt; dst = pt; K = 27; CIN = 64;  break;
        case 2:  src = w2; dst = p2; K = 9;  CIN = 64;  break;
        case 3:  src = w3; dst = p3; K = 9;  CIN = 64;  break;
        default: src = w4; dst = p4; K = 27; CIN = 64;  break;
    }
    int S = CIN / 16;
    int F = K * S * 2 * 64;
    if (t >= F) return;
    int lane = t & 63;
    int r = t >> 6;
    int nt = r & 1; r >>= 1;
    int s = r % S;
    int k = r / S;
    int c = nt * 32 + (lane & 31);
    int cib = s * 16 + (lane >> 5) * 8;
    #pragma unroll
    for (int j = 0; j < 8; ++j)
        dst[(size_t)t * 8 + j] = f2bf(src[((size_t)k * CIN + cib + j) * 64 + c]);
}

// --- one sparse-conv layer ---------------------------------------------------
// MODE 0: BN+LeakyReLU -> bf16   MODE 1: +skip -> bf16   MODE 2: BN+LeakyReLU -> f32
template <int CIN, int MODE>
__global__ __launch_bounds__(64)
void conv_layer(const uint16_t* __restrict__ feats,  // [N][CIN] bf16
                const uint16_t* __restrict__ wf,     // packed [K][CIN/16][2][64][8] bf16
                const int* __restrict__ nbr,         // [K][N]
                const int K, const int npts,
                const float* __restrict__ bnp,       // [2][64] scale/shift (or null)
                const float* __restrict__ skip,      // [N][64] f32 (or null)
                uint16_t* __restrict__ outb,
                float* __restrict__ outf) {
    constexpr int S = CIN / 16;
    const int lane = threadIdx.x;
    const int l31  = lane & 31;
    const int hi   = lane >> 5;          // 0/1: which K-half of the fragment
    const int base = blockIdx.x * 64;    // this wave's 64 output rows
    const int r0 = base + l31;           // m-tile 0 row for this lane
    const int r1 = r0 + 32;              // m-tile 1 row
    const int g0 = min(r0, npts - 1);
    const int g1 = min(r1, npts - 1);

    f32x16 acc00 = {0,0,0,0,0,0,0,0,0,0,0,0,0,0,0,0};
    f32x16 acc01 = {0,0,0,0,0,0,0,0,0,0,0,0,0,0,0,0};
    f32x16 acc10 = {0,0,0,0,0,0,0,0,0,0,0,0,0,0,0,0};
    f32x16 acc11 = {0,0,0,0,0,0,0,0,0,0,0,0,0,0,0,0};

    for (int k = 0; k < K; ++k) {
        const int i0 = nbr[(size_t)k * npts + g0];
        const int i1 = nbr[(size_t)k * npts + g1];
        const uint16_t* a0p = feats + (size_t)i0 * CIN + hi * 8;
        const uint16_t* a1p = feats + (size_t)i1 * CIN + hi * 8;
        const uint16_t* bp  = wf + (size_t)k * (S * 1024) + lane * 8;
        #pragma unroll
        for (int s = 0; s < S; ++s) {
            bf16x8 a0 = ldb8(a0p + s * 16);
            bf16x8 a1 = ldb8(a1p + s * 16);
            bf16x8 b0 = ldb8(bp + s * 1024);
            bf16x8 b1 = ldb8(bp + s * 1024 + 512);
            acc00 = __builtin_amdgcn_mfma_f32_32x32x16_bf16(a0, b0, acc00, 0, 0, 0);
            acc01 = __builtin_amdgcn_mfma_f32_32x32x16_bf16(a0, b1, acc01, 0, 0, 0);
            acc10 = __builtin_amdgcn_mfma_f32_32x32x16_bf16(a1, b0, acc10, 0, 0, 0);
            acc11 = __builtin_amdgcn_mfma_f32_32x32x16_bf16(a1, b1, acc11, 0, 0, 0);
        }
    }

    const int c0 = l31, c1 = 32 + l31;
    float sc0 = 0.f, sh0 = 0.f, sc1 = 0.f, sh1 = 0.f;
    if (MODE != 1) {
        sc0 = bnp[c0]; sh0 = bnp[64 + c0];
        sc1 = bnp[c1]; sh1 = bnp[64 + c1];
    }
    #pragma unroll
    for (int reg = 0; reg < 16; ++reg) {
        const int row = (reg & 3) + 8 * (reg >> 2) + 4 * hi;
        const int gr0 = base + row;
        const int gr1 = base + 32 + row;
        float v00 = acc00[reg], v01 = acc01[reg];
        float v10 = acc10[reg], v11 = acc11[reg];
        if (MODE != 1) {
            v00 = v00 * sc0 + sh0; v00 = v00 >= 0.f ? v00 : 0.01f * v00;
            v01 = v01 * sc1 + sh1; v01 = v01 >= 0.f ? v01 : 0.01f * v01;
            v10 = v10 * sc0 + sh0; v10 = v10 >= 0.f ? v10 : 0.01f * v10;
            v11 = v11 * sc1 + sh1; v11 = v11 >= 0.f ? v11 : 0.01f * v11;
        }
        if (gr0 < npts) {
            if (MODE == 1) { v00 += skip[(size_t)gr0 * 64 + c0]; v01 += skip[(size_t)gr0 * 64 + c1]; }
            if (MODE == 2) {
                outf[(size_t)gr0 * 64 + c0] = v00; outf[(size_t)gr0 * 64 + c1] = v01;
            } else {
                outb[(size_t)gr0 * 64 + c0] = f2bf(v00); outb[(size_t)gr0 * 64 + c1] = f2bf(v01);
            }
        }
        if (gr1 < npts) {
            if (MODE == 1) { v10 += skip[(size_t)gr1 * 64 + c0]; v11 += skip[(size_t)gr1 * 64 + c1]; }
            if (MODE == 2) {
                outf[(size_t)gr1 * 64 + c0] = v10; outf[(size_t)gr1 * 64 + c1] = v11;
            } else {
                outb[(size_t)gr1 * 64 + c0] = f2bf(v10); outb[(size_t)gr1 * 64 + c1] = f2bf(v11);
            }
        }
    }
}

extern "C" void kernel_launch(void* const* d_in, const int* in_sizes, int n_in,
                              void* d_out, int out_size, void* d_ws, size_t ws_size,
                              hipStream_t stream) {
    const int N = in_sizes[0] / 128;
    const float* x    = (const float*)d_in[0];
    const float* skip = (const float*)d_in[1];
    const float* W1   = (const float*)d_in[2];
    const float* Wt   = (const float*)d_in[3];
    const float* W2   = (const float*)d_in[4];
    const float* W3   = (const float*)d_in[5];
    const float* W4   = (const float*)d_in[6];
    const float* bn   = (const float*)d_in[7];
    const int* nbr1   = (const int*)d_in[8];
    const int* nbrt   = (const int*)d_in[9];
    const int* nbr2   = (const int*)d_in[10];
    const int* nbr3   = (const int*)d_in[11];
    const int* nbr4   = (const int*)d_in[12];

    uint8_t* ws = (uint8_t*)d_ws;
    size_t off = 0;
    auto carve = [&](size_t bytes) -> void* {
        void* p = ws + off;
        off += (bytes + 255) & ~(size_t)255;
        return p;
    };
    uint16_t* xb  = (uint16_t*)carve((size_t)N * 128 * 2);
    uint16_t* hA  = (uint16_t*)carve((size_t)N * 64 * 2);
    uint16_t* hB  = (uint16_t*)carve((size_t)N * 64 * 2);
    uint16_t* p1  = (uint16_t*)carve((size_t)27 * 128 * 64 * 2);
    uint16_t* pt  = (uint16_t*)carve((size_t)27 * 64 * 64 * 2);
    uint16_t* p2  = (uint16_t*)carve((size_t)9 * 64 * 64 * 2);
    uint16_t* p3  = (uint16_t*)carve((size_t)9 * 64 * 64 * 2);
    uint16_t* p4  = (uint16_t*)carve((size_t)27 * 64 * 64 * 2);
    float*    bnp = (float*)carve((size_t)4 * 2 * 64 * 4);

    // prologue: convert + pack (re-done every call; ws is re-poisoned)
    const int n8 = N * 16;  // N*128/8
    convert_x<<<(n8 + 255) / 256, 256, 0, stream>>>(x, xb, n8);
    pack_weights<<<dim3(108, 6), 256, 0, stream>>>(W1, Wt, W2, W3, W4, bn,
                                                   p1, pt, p2, p3, p4, bnp);

    const int grid = (N + 63) / 64;
    conv_layer<128, 0><<<grid, 64, 0, stream>>>(xb, p1, nbr1, 27, N, bnp + 0,   nullptr, hA, nullptr);
    conv_layer<64,  1><<<grid, 64, 0, stream>>>(hA, pt, nbrt, 27, N, nullptr,   skip,    hB, nullptr);
    conv_layer<64,  0><<<grid, 64, 0, stream>>>(hB, p2, nbr2, 9,  N, bnp + 128, nullptr, hA, nullptr);
    conv_layer<64,  0><<<grid, 64, 0, stream>>>(hA, p3, nbr3, 9,  N, bnp + 256, nullptr, hB, nullptr);
    conv_layer<64,  2><<<grid, 64, 0, stream>>>(hB, p4, nbr4, 27, N, bnp + 384, nullptr, nullptr, (float*)d_out);
}